// Round 1
// baseline (1649.950 us; speedup 1.0000x reference)
//
#include <hip/hip_runtime.h>
#include <math.h>

#define HH 512
#define WW 512
#define CC 64
#define BB 4

// ---------------- kernel 1: styles = ws @ (aw.T * g) + ab ----------------
__global__ void k_styles(const float* __restrict__ wsv,      // [B,512]
                         const float* __restrict__ aw,       // [64,512]
                         const float* __restrict__ ab,       // [64]
                         float* __restrict__ styles) {       // [B,64]
    int bid = blockIdx.x;          // 0..255  -> (b, ci)
    int b = bid >> 6, ci = bid & 63;
    int l = threadIdx.x;           // 0..63 (one wave)
    const float* wrow = wsv + b * 512;
    const float* arow = aw + ci * 512;
    float s = 0.f;
    #pragma unroll
    for (int j = 0; j < 8; ++j)
        s += wrow[l + 64 * j] * arow[l + 64 * j];
    #pragma unroll
    for (int off = 32; off; off >>= 1)
        s += __shfl_xor(s, off, 64);
    if (l == 0)
        styles[b * 64 + ci] = s * 0.044194173824159216f /* 1/sqrt(512) */ + ab[ci];
}

// ------------- kernel 2: modulate + demodulate, store [B][Ci][Co][9] -------------
__global__ void k_wmod(const float* __restrict__ cw,      // [64,64,3,3]
                       const float* __restrict__ styles,  // [B,64]
                       float* __restrict__ wbuf) {        // [B,Ci,Co,9]
    int b = blockIdx.x >> 6, co = blockIdx.x & 63;
    int ci = threadIdx.x;   // 64 threads = 1 wave
    float st = styles[b * 64 + ci];
    const float* wp = cw + (co * 64 + ci) * 9;
    float wv[9];
    float ss = 0.f;
    #pragma unroll
    for (int k = 0; k < 9; ++k) { wv[k] = wp[k] * st; ss += wv[k] * wv[k]; }
    #pragma unroll
    for (int off = 32; off; off >>= 1)
        ss += __shfl_xor(ss, off, 64);
    float dm = 1.0f / sqrtf(ss + 1e-8f);
    float* op = wbuf + ((size_t)(b * 64 + ci) * 64 + co) * 9;
    #pragma unroll
    for (int k = 0; k < 9; ++k) op[k] = wv[k] * dm;
}

// ------------- kernel 3: grouped 3x3 conv + noise + bias + lrelu*sqrt2 + clamp -------------
// Block: 256 threads. Spatial tile 64x16, 16 output channels per block.
// Thread t: col = t&63, base row r0 = t>>6, handles rows r0, r0+4, r0+8, r0+12.
__global__ __launch_bounds__(256) void k_conv(
    const float* __restrict__ x,      // [B,64,512,512]
    const float* __restrict__ wbuf,   // [B,Ci,Co,9]
    const float* __restrict__ noise,  // [B,1,512,512]
    const float* __restrict__ bias,   // [64]
    float* __restrict__ out) {        // [B,64,512,512]
    const int t   = threadIdx.x;
    const int b   = blockIdx.z;
    const int cob = blockIdx.y * 16;
    const int sp  = blockIdx.x;          // 0..255
    const int tx  = (sp & 7) * 64;
    const int ty  = (sp >> 3) * 16;
    const int col = t & 63;
    const int r0  = t >> 6;

    __shared__ float xt[18 * 66];        // (16+2) x (64+2) halo tile

    float acc[16][4];
    #pragma unroll
    for (int c = 0; c < 16; ++c)
        #pragma unroll
        for (int p = 0; p < 4; ++p) acc[c][p] = 0.f;

    const float* xb = x + (size_t)b * 64 * (HH * WW);

    for (int ci = 0; ci < 64; ++ci) {
        __syncthreads();
        const float* xc = xb + (size_t)ci * (HH * WW);
        #pragma unroll
        for (int it = 0; it < 5; ++it) {
            int idx = t + it * 256;
            if (idx < 18 * 66) {
                int row = idx / 66, c2 = idx - row * 66;
                int gy = ty + row - 1, gx = tx + c2 - 1;
                float v = 0.f;
                if (gy >= 0 && gy < HH && gx >= 0 && gx < WW)
                    v = xc[gy * WW + gx];
                xt[idx] = v;
            }
        }
        __syncthreads();

        // load this thread's 4 pixels' 3x3 neighborhoods (36 distinct values)
        float xv[4][9];
        #pragma unroll
        for (int p = 0; p < 4; ++p)
            #pragma unroll
            for (int dy = 0; dy < 3; ++dy)
                #pragma unroll
                for (int dx = 0; dx < 3; ++dx)
                    xv[p][3 * dy + dx] = xt[(r0 + 4 * p + dy) * 66 + col + dx];

        const float* wp = wbuf + ((size_t)((b * 64 + ci) * 64) + cob) * 9;
        #pragma unroll
        for (int co = 0; co < 16; ++co) {
            const float* w = wp + co * 9;   // uniform across block -> scalar loads
            float w0 = w[0], w1 = w[1], w2 = w[2], w3 = w[3], w4 = w[4],
                  w5 = w[5], w6 = w[6], w7 = w[7], w8 = w[8];
            #pragma unroll
            for (int p = 0; p < 4; ++p) {
                float a = acc[co][p];
                a = fmaf(xv[p][0], w0, a);
                a = fmaf(xv[p][1], w1, a);
                a = fmaf(xv[p][2], w2, a);
                a = fmaf(xv[p][3], w3, a);
                a = fmaf(xv[p][4], w4, a);
                a = fmaf(xv[p][5], w5, a);
                a = fmaf(xv[p][6], w6, a);
                a = fmaf(xv[p][7], w7, a);
                a = fmaf(xv[p][8], w8, a);
                acc[co][p] = a;
            }
        }
    }

    // epilogue: +noise, +bias, lrelu*sqrt(2), clamp
    const float* nz = noise + (size_t)b * (HH * WW);
    float nv[4];
    #pragma unroll
    for (int p = 0; p < 4; ++p)
        nv[p] = nz[(ty + r0 + 4 * p) * WW + tx + col];
    #pragma unroll
    for (int co = 0; co < 16; ++co) {
        float bs = bias[cob + co];
        #pragma unroll
        for (int p = 0; p < 4; ++p) {
            float y = acc[co][p] + nv[p] + bs;
            y = (y >= 0.f ? y : 0.2f * y) * 1.41421356f;
            y = fminf(fmaxf(y, -256.f), 256.f);
            out[((size_t)(b * 64 + cob + co) * HH + (ty + r0 + 4 * p)) * WW + tx + col] = y;
        }
    }
}

extern "C" void kernel_launch(void* const* d_in, const int* in_sizes, int n_in,
                              void* d_out, int out_size, void* d_ws, size_t ws_size,
                              hipStream_t stream) {
    const float* x     = (const float*)d_in[0];
    const float* wsv   = (const float*)d_in[1];
    const float* noise = (const float*)d_in[2];
    const float* aw    = (const float*)d_in[3];
    const float* ab    = (const float*)d_in[4];
    const float* cw    = (const float*)d_in[5];
    const float* bias  = (const float*)d_in[6];
    float* out = (float*)d_out;

    float* ws0    = (float*)d_ws;
    float* styles = ws0;         // 256 floats
    float* wbuf   = ws0 + 256;   // 4*64*64*9 = 147456 floats

    k_styles<<<256, 64, 0, stream>>>(wsv, aw, ab, styles);
    k_wmod<<<256, 64, 0, stream>>>(cw, styles, wbuf);
    dim3 grid(256, 4, 4);
    k_conv<<<grid, 256, 0, stream>>>(x, wbuf, noise, bias, out);
}

// Round 2
// 317.315 us; speedup vs baseline: 5.1997x; 5.1997x over previous
//
#include <hip/hip_runtime.h>
#include <math.h>

#define HH 512
#define WW 512

typedef short bf16x8 __attribute__((ext_vector_type(8)));
typedef float f32x4 __attribute__((ext_vector_type(4)));

__device__ __forceinline__ ushort f2bf(float f) {
    union { float f; uint u; } c; c.f = f;
    uint u = c.u;
    return (ushort)((u + 0x7fffu + ((u >> 16) & 1u)) >> 16);
}

// ---------------- kernel 1: styles = ws @ (aw.T / sqrt(512)) + ab ----------------
__global__ void k_styles(const float* __restrict__ wsv,      // [B,512]
                         const float* __restrict__ aw,       // [64,512]
                         const float* __restrict__ ab,       // [64]
                         float* __restrict__ styles) {       // [B,64]
    int bid = blockIdx.x;
    int b = bid >> 6, ci = bid & 63;
    int l = threadIdx.x;
    const float* wrow = wsv + b * 512;
    const float* arow = aw + ci * 512;
    float s = 0.f;
    #pragma unroll
    for (int j = 0; j < 8; ++j)
        s += wrow[l + 64 * j] * arow[l + 64 * j];
    #pragma unroll
    for (int off = 32; off; off >>= 1)
        s += __shfl_xor(s, off, 64);
    if (l == 0)
        styles[b * 64 + ci] = s * 0.044194173824159216f + ab[ci];
}

// ------------- kernel 2: modulate + demodulate -> bf16 [b][k(9)][co][ci] -------------
__global__ void k_wmod(const float* __restrict__ cw,      // [64,64,3,3]
                       const float* __restrict__ styles,  // [B,64]
                       ushort* __restrict__ wb) {         // [B,9,64,64] bf16
    int b = blockIdx.x >> 6, co = blockIdx.x & 63;
    int ci = threadIdx.x;   // one wave
    float st = styles[b * 64 + ci];
    const float* wp = cw + (co * 64 + ci) * 9;
    float wv[9];
    float ss = 0.f;
    #pragma unroll
    for (int k = 0; k < 9; ++k) { wv[k] = wp[k] * st; ss += wv[k] * wv[k]; }
    #pragma unroll
    for (int off = 32; off; off >>= 1)
        ss += __shfl_xor(ss, off, 64);
    float dm = 1.0f / sqrtf(ss + 1e-8f);
    #pragma unroll
    for (int k = 0; k < 9; ++k)
        wb[((size_t)(b * 9 + k) * 64 + co) * 64 + ci] = f2bf(wv[k] * dm);
}

// ------------- kernel 3: MFMA implicit-GEMM conv + epilogue -------------
// Block: 256 threads (4 waves). Output tile: 64 co x (8 rows x 32 cols).
// LDS: x tile [lrow 10][lcol 34][ci 64] bf16, ci swizzled by (lcol&7)<<3.
// Wave w: all 4 m-tiles (co) x n-tiles {4w..4w+3} (16 px each).
__global__ __launch_bounds__(256, 3) void k_conv(
    const float* __restrict__ x,      // [B,64,512,512] fp32
    const ushort* __restrict__ wb,    // [B,9,64,64] bf16
    const float* __restrict__ noise,  // [B,1,512,512]
    const float* __restrict__ bias,   // [64]
    float* __restrict__ out) {        // [B,64,512,512] fp32
    __shared__ ushort xt[10 * 34 * 64];   // 43520 B

    const int t = threadIdx.x;
    const int b = blockIdx.y;
    const int colb = blockIdx.x & 15;
    const int rowb = blockIdx.x >> 4;
    const int tx = colb * 32, ty = rowb * 8;

    const float* xb = x + (size_t)b * 64 * (HH * WW);

    // ---- staging: 1600 tasks = lrow(10) x g(10) x cg(16), cg fastest ----
    #pragma unroll
    for (int r = 0; r < 7; ++r) {
        int id = t + r * 256;
        if (id < 1600) {
            int cg = id & 15;
            int rg = id >> 4;          // 0..99
            int g = rg % 10;
            int lrow = rg / 10;
            int gy = ty - 1 + lrow;
            int gx0 = tx - 4 + g * 4;  // 16B-aligned float4 window
            f32x4 v[4];
            bool ok = (gy >= 0) && (gy < HH) && (gx0 >= 0) && (gx0 <= WW - 4);
            if (ok) {
                const float* p = xb + (size_t)(cg * 4) * (HH * WW) + (size_t)gy * WW + gx0;
                #pragma unroll
                for (int i = 0; i < 4; ++i)
                    v[i] = *(const f32x4*)(p + (size_t)i * (HH * WW));
            } else {
                #pragma unroll
                for (int i = 0; i < 4; ++i) v[i] = (f32x4){0.f, 0.f, 0.f, 0.f};
            }
            #pragma unroll
            for (int e = 0; e < 4; ++e) {
                int lcol = g * 4 + e - 3;
                if (lcol >= 0 && lcol < 34) {
                    uint lo = (uint)f2bf(v[0][e]) | ((uint)f2bf(v[1][e]) << 16);
                    uint hi = (uint)f2bf(v[2][e]) | ((uint)f2bf(v[3][e]) << 16);
                    int cib = (cg * 4) ^ ((lcol & 7) << 3);
                    uint2* dst = (uint2*)&xt[(lrow * 34 + lcol) * 64 + cib];
                    *dst = make_uint2(lo, hi);
                }
            }
        }
    }
    __syncthreads();

    // ---- compute ----
    const int w = t >> 6;
    const int lane = t & 63;
    const int lr = lane & 15;
    const int lq = lane >> 4;

    // B-frag base LDS indices (dy=0, kb=0) for i (n-tile) x dx
    int bidx[4][3];
    #pragma unroll
    for (int i = 0; i < 4; ++i) {
        int nt = 4 * w + i;
        int prow = nt >> 1;
        int c = (nt & 1) * 16 + lr;
        #pragma unroll
        for (int dx = 0; dx < 3; ++dx) {
            int lcol = c + dx;
            bidx[i][dx] = (prow * 34 + lcol) * 64 + ((lq * 8) ^ ((lcol & 7) << 3));
        }
    }

    const ushort* wbb = wb + (size_t)b * 9 * 64 * 64 + lr * 64 + lq * 8;

    f32x4 acc[4][4];
    #pragma unroll
    for (int m = 0; m < 4; ++m)
        #pragma unroll
        for (int i = 0; i < 4; ++i) acc[m][i] = (f32x4){0.f, 0.f, 0.f, 0.f};

    #pragma unroll
    for (int dy = 0; dy < 3; ++dy) {
        #pragma unroll
        for (int dx = 0; dx < 3; ++dx) {
            #pragma unroll
            for (int kb = 0; kb < 2; ++kb) {
                const int off = dy * 3 + dx;
                bf16x8 afr[4], bfr[4];
                #pragma unroll
                for (int m = 0; m < 4; ++m)
                    afr[m] = *(const bf16x8*)(wbb + off * 4096 + m * 1024 + kb * 32);
                #pragma unroll
                for (int i = 0; i < 4; ++i) {
                    int idx = (bidx[i][dx] + dy * (34 * 64)) ^ (kb * 32);
                    bfr[i] = *(const bf16x8*)&xt[idx];
                }
                #pragma unroll
                for (int m = 0; m < 4; ++m)
                    #pragma unroll
                    for (int i = 0; i < 4; ++i)
                        acc[m][i] = __builtin_amdgcn_mfma_f32_16x16x32_bf16(
                            afr[m], bfr[i], acc[m][i], 0, 0, 0);
            }
        }
    }

    // ---- epilogue: +noise, +bias, lrelu*sqrt2, clamp, store ----
    const float* nz = noise + (size_t)b * (HH * WW);
    float nv[4];
    int gyv[4], gxv[4];
    #pragma unroll
    for (int i = 0; i < 4; ++i) {
        int nt = 4 * w + i;
        int prow = nt >> 1;
        int pcol = (nt & 1) * 16 + lr;
        gyv[i] = ty + prow;
        gxv[i] = tx + pcol;
        nv[i] = nz[gyv[i] * WW + gxv[i]];
    }
    #pragma unroll
    for (int m = 0; m < 4; ++m) {
        f32x4 bv = *(const f32x4*)&bias[m * 16 + lq * 4];
        #pragma unroll
        for (int i = 0; i < 4; ++i) {
            #pragma unroll
            for (int rg2 = 0; rg2 < 4; ++rg2) {
                int co = m * 16 + lq * 4 + rg2;
                float y = acc[m][i][rg2] + nv[i] + bv[rg2];
                y = (y >= 0.f ? y : 0.2f * y) * 1.41421356237f;
                y = fminf(fmaxf(y, -256.f), 256.f);
                out[((size_t)(b * 64 + co) * HH + gyv[i]) * WW + gxv[i]] = y;
            }
        }
    }
}

extern "C" void kernel_launch(void* const* d_in, const int* in_sizes, int n_in,
                              void* d_out, int out_size, void* d_ws, size_t ws_size,
                              hipStream_t stream) {
    const float* x     = (const float*)d_in[0];
    const float* wsv   = (const float*)d_in[1];
    const float* noise = (const float*)d_in[2];
    const float* aw    = (const float*)d_in[3];
    const float* ab    = (const float*)d_in[4];
    const float* cw    = (const float*)d_in[5];
    const float* bias  = (const float*)d_in[6];
    float* out = (float*)d_out;

    float*  styles = (float*)d_ws;                       // 256 floats
    ushort* wb16   = (ushort*)((char*)d_ws + 1024);      // 4*9*64*64 bf16 = 294912 B

    k_styles<<<256, 64, 0, stream>>>(wsv, aw, ab, styles);
    k_wmod<<<256, 64, 0, stream>>>(cw, styles, wb16);
    dim3 grid(1024, 4);
    k_conv<<<grid, 256, 0, stream>>>(x, wb16, noise, bias, out);
}

// Round 3
// 287.397 us; speedup vs baseline: 5.7410x; 1.1041x over previous
//
#include <hip/hip_runtime.h>
#include <math.h>

#define HH 512
#define WW 512

typedef short bf16x8 __attribute__((ext_vector_type(8)));
typedef float f32x4 __attribute__((ext_vector_type(4)));

__device__ __forceinline__ ushort f2bf(float f) {
    union { float f; uint u; } c; c.f = f;
    uint u = c.u;
    return (ushort)((u + 0x7fffu + ((u >> 16) & 1u)) >> 16);
}

// ---------------- kernel 1: styles = ws @ (aw.T / sqrt(512)) + ab ----------------
__global__ void k_styles(const float* __restrict__ wsv,      // [B,512]
                         const float* __restrict__ aw,       // [64,512]
                         const float* __restrict__ ab,       // [64]
                         float* __restrict__ styles) {       // [B,64]
    int bid = blockIdx.x;
    int b = bid >> 6, ci = bid & 63;
    int l = threadIdx.x;
    const float* wrow = wsv + b * 512;
    const float* arow = aw + ci * 512;
    float s = 0.f;
    #pragma unroll
    for (int j = 0; j < 8; ++j)
        s += wrow[l + 64 * j] * arow[l + 64 * j];
    #pragma unroll
    for (int off = 32; off; off >>= 1)
        s += __shfl_xor(s, off, 64);
    if (l == 0)
        styles[b * 64 + ci] = s * 0.044194173824159216f + ab[ci];
}

// ------------- kernel 2: modulate + demodulate -> bf16 [b][k(9)][co][ci] -------------
__global__ void k_wmod(const float* __restrict__ cw,      // [64,64,3,3]
                       const float* __restrict__ styles,  // [B,64]
                       ushort* __restrict__ wb) {         // [B,9,64,64] bf16
    int b = blockIdx.x >> 6, co = blockIdx.x & 63;
    int ci = threadIdx.x;   // one wave
    float st = styles[b * 64 + ci];
    const float* wp = cw + (co * 64 + ci) * 9;
    float wv[9];
    float ss = 0.f;
    #pragma unroll
    for (int k = 0; k < 9; ++k) { wv[k] = wp[k] * st; ss += wv[k] * wv[k]; }
    #pragma unroll
    for (int off = 32; off; off >>= 1)
        ss += __shfl_xor(ss, off, 64);
    float dm = 1.0f / sqrtf(ss + 1e-8f);
    #pragma unroll
    for (int k = 0; k < 9; ++k)
        wb[((size_t)(b * 9 + k) * 64 + co) * 64 + ci] = f2bf(wv[k] * dm);
}

// ------------- kernel 3: MFMA implicit-GEMM conv + epilogue -------------
// Block: 256 threads (4 waves). Output tile: 64 co x (8 rows x 32 cols).
// LDS: x tile [lrow 10][lcol 34][ci 64] bf16, ci swizzled by (lcol&7)<<3.
// Staging task order: g (col group) lane-fastest -> wave reads contiguous
// 160B row segments within ONE ci plane per instruction (DRAM locality).
__global__ __launch_bounds__(256, 3) void k_conv(
    const float* __restrict__ x,      // [B,64,512,512] fp32
    const ushort* __restrict__ wb,    // [B,9,64,64] bf16
    const float* __restrict__ noise,  // [B,1,512,512]
    const float* __restrict__ bias,   // [64]
    float* __restrict__ out) {        // [B,64,512,512] fp32
    __shared__ ushort xt[10 * 34 * 64];   // 43520 B

    const int t = threadIdx.x;
    const int b = blockIdx.y;
    const int colb = blockIdx.x & 15;
    const int rowb = blockIdx.x >> 4;
    const int tx = colb * 32, ty = rowb * 8;

    const float* xb = x + (size_t)b * 64 * (HH * WW);

    // ---- staging: 1600 tasks = cg(16) x lrow(10) x g(10), g lane-fastest ----
    #pragma unroll
    for (int r = 0; r < 7; ++r) {
        int id = t + r * 256;
        if (id < 1600) {
            int g = id % 10;
            int tmp = id / 10;
            int lrow = tmp % 10;
            int cg = tmp / 10;         // 0..15 (group of 4 ci planes)
            int gy = ty - 1 + lrow;
            int gx0 = tx - 4 + g * 4;  // 16B-aligned float4 window
            f32x4 v[4];
            bool ok = (gy >= 0) && (gy < HH) && (gx0 >= 0) && (gx0 <= WW - 4);
            if (ok) {
                const float* p = xb + (size_t)(cg * 4) * (HH * WW) + (size_t)gy * WW + gx0;
                #pragma unroll
                for (int i = 0; i < 4; ++i)
                    v[i] = *(const f32x4*)(p + (size_t)i * (HH * WW));
            } else {
                #pragma unroll
                for (int i = 0; i < 4; ++i) v[i] = (f32x4){0.f, 0.f, 0.f, 0.f};
            }
            #pragma unroll
            for (int e = 0; e < 4; ++e) {
                int lcol = g * 4 + e - 3;
                if (lcol >= 0 && lcol < 34) {
                    uint lo = (uint)f2bf(v[0][e]) | ((uint)f2bf(v[1][e]) << 16);
                    uint hi = (uint)f2bf(v[2][e]) | ((uint)f2bf(v[3][e]) << 16);
                    int cib = (cg * 4) ^ ((lcol & 7) << 3);
                    uint2* dst = (uint2*)&xt[(lrow * 34 + lcol) * 64 + cib];
                    *dst = make_uint2(lo, hi);
                }
            }
        }
    }
    __syncthreads();

    // ---- compute ----
    const int w = t >> 6;
    const int lane = t & 63;
    const int lr = lane & 15;
    const int lq = lane >> 4;

    // B-frag base LDS indices (dy=0, kb=0) for i (n-tile) x dx
    int bidx[4][3];
    #pragma unroll
    for (int i = 0; i < 4; ++i) {
        int nt = 4 * w + i;
        int prow = nt >> 1;
        int c = (nt & 1) * 16 + lr;
        #pragma unroll
        for (int dx = 0; dx < 3; ++dx) {
            int lcol = c + dx;
            bidx[i][dx] = (prow * 34 + lcol) * 64 + ((lq * 8) ^ ((lcol & 7) << 3));
        }
    }

    const ushort* wbb = wb + (size_t)b * 9 * 64 * 64 + lr * 64 + lq * 8;

    f32x4 acc[4][4];
    #pragma unroll
    for (int m = 0; m < 4; ++m)
        #pragma unroll
        for (int i = 0; i < 4; ++i) acc[m][i] = (f32x4){0.f, 0.f, 0.f, 0.f};

    #pragma unroll
    for (int dy = 0; dy < 3; ++dy) {
        #pragma unroll
        for (int dx = 0; dx < 3; ++dx) {
            #pragma unroll
            for (int kb = 0; kb < 2; ++kb) {
                const int off = dy * 3 + dx;
                bf16x8 afr[4], bfr[4];
                #pragma unroll
                for (int m = 0; m < 4; ++m)
                    afr[m] = *(const bf16x8*)(wbb + off * 4096 + m * 1024 + kb * 32);
                #pragma unroll
                for (int i = 0; i < 4; ++i) {
                    int idx = (bidx[i][dx] + dy * (34 * 64)) ^ (kb * 32);
                    bfr[i] = *(const bf16x8*)&xt[idx];
                }
                #pragma unroll
                for (int m = 0; m < 4; ++m)
                    #pragma unroll
                    for (int i = 0; i < 4; ++i)
                        acc[m][i] = __builtin_amdgcn_mfma_f32_16x16x32_bf16(
                            afr[m], bfr[i], acc[m][i], 0, 0, 0);
            }
        }
    }

    // ---- epilogue: +noise, +bias, lrelu*sqrt2, clamp, store ----
    const float* nz = noise + (size_t)b * (HH * WW);
    float nv[4];
    int gyv[4], gxv[4];
    #pragma unroll
    for (int i = 0; i < 4; ++i) {
        int nt = 4 * w + i;
        int prow = nt >> 1;
        int pcol = (nt & 1) * 16 + lr;
        gyv[i] = ty + prow;
        gxv[i] = tx + pcol;
        nv[i] = nz[gyv[i] * WW + gxv[i]];
    }
    #pragma unroll
    for (int m = 0; m < 4; ++m) {
        f32x4 bv = *(const f32x4*)&bias[m * 16 + lq * 4];
        #pragma unroll
        for (int i = 0; i < 4; ++i) {
            #pragma unroll
            for (int rg2 = 0; rg2 < 4; ++rg2) {
                int co = m * 16 + lq * 4 + rg2;
                float y = acc[m][i][rg2] + nv[i] + bv[rg2];
                y = (y >= 0.f ? y : 0.2f * y) * 1.41421356237f;
                y = fminf(fmaxf(y, -256.f), 256.f);
                out[((size_t)(b * 64 + co) * HH + gyv[i]) * WW + gxv[i]] = y;
            }
        }
    }
}

extern "C" void kernel_launch(void* const* d_in, const int* in_sizes, int n_in,
                              void* d_out, int out_size, void* d_ws, size_t ws_size,
                              hipStream_t stream) {
    const float* x     = (const float*)d_in[0];
    const float* wsv   = (const float*)d_in[1];
    const float* noise = (const float*)d_in[2];
    const float* aw    = (const float*)d_in[3];
    const float* ab    = (const float*)d_in[4];
    const float* cw    = (const float*)d_in[5];
    const float* bias  = (const float*)d_in[6];
    float* out = (float*)d_out;

    float*  styles = (float*)d_ws;                       // 256 floats
    ushort* wb16   = (ushort*)((char*)d_ws + 1024);      // 4*9*64*64 bf16 = 294912 B

    k_styles<<<256, 64, 0, stream>>>(wsv, aw, ab, styles);
    k_wmod<<<256, 64, 0, stream>>>(cw, styles, wb16);
    dim3 grid(1024, 4);
    k_conv<<<grid, 256, 0, stream>>>(x, wb16, noise, bias, out);
}